// Round 1
// baseline (363.717 us; speedup 1.0000x reference)
//
#include <hip/hip_runtime.h>

#define F      128       // feature width
#define DCAP   40        // per-node edge capacity (deg ~ Poisson(16); P(deg>40) ~ 1e-24)
#define OVFCAP 32768     // spill-list capacity (cold correctness path, never fires @ graded dist)
#define NPW    16        // nodes per wave in gather
#define BR     64        // rows per fp32-GEMM block tile (fallback)
#define KC     32        // k-chunk (fallback GEMM)

typedef short bf16x8 __attribute__((ext_vector_type(8)));
typedef float f32x4  __attribute__((ext_vector_type(4)));

__device__ __forceinline__ unsigned short f32_to_bf16_rne(float x) {
    unsigned u = __float_as_uint(x);
    u += 0x7fffu + ((u >> 16) & 1u);
    return (unsigned short)(u >> 16);
}
__device__ __forceinline__ float bf16_to_f32(unsigned short u) {
    return __uint_as_float((unsigned)u << 16);
}

// ---------------------------------------------------------------------------
// Kernel 0: convert W fp32 -> bf16 (64 KB only).
// ---------------------------------------------------------------------------
__global__ __launch_bounds__(256) void conv_w_kernel(
        const float* __restrict__ Wf, unsigned short* __restrict__ Wb, int n4) {
    int i = blockIdx.x * blockDim.x + threadIdx.x;
    if (i < n4) {
        float4 v = *(const float4*)(Wf + 4 * (long)i);
        ushort4 o;
        o.x = f32_to_bf16_rne(v.x);
        o.y = f32_to_bf16_rne(v.y);
        o.z = f32_to_bf16_rne(v.z);
        o.w = f32_to_bf16_rne(v.w);
        *(ushort4*)(Wb + 4 * (long)i) = o;
    }
}

// ---------------------------------------------------------------------------
// Kernel 1: h' = h @ W^T via MFMA bf16 (unchanged from prior round).
// Algebraic reorder: segment_sum(h[src]) @ W^T == segment_sum((h@W^T)[src]).
// C layout (measured m89/m91): col=lane&15, row=quad*4+reg.
// ---------------------------------------------------------------------------
__global__ __launch_bounds__(256) void gemm_h_kernel(
        const float* __restrict__ h,
        const unsigned short* __restrict__ Wb,
        unsigned short* __restrict__ hp,          // [n+1][128] bf16 out (row n = zeros)
        int n_rows) {
    const int wave = (blockIdx.x * 256 + threadIdx.x) >> 6;
    const int lane = threadIdx.x & 63;
    const int m0 = wave * 16;
    if (m0 >= n_rows) return;
    const int mn   = lane & 15;
    const int quad = lane >> 4;

    const int rowc = min(m0 + mn, n_rows - 1);
    const float* arow = h + (long)rowc * F + quad * 8;

    bf16x8 afr[4];
    #pragma unroll
    for (int kk = 0; kk < 4; ++kk) {
        float4 p0 = *(const float4*)(arow + kk * 32);
        float4 p1 = *(const float4*)(arow + kk * 32 + 4);
        bf16x8 f;
        f[0] = (short)f32_to_bf16_rne(p0.x);
        f[1] = (short)f32_to_bf16_rne(p0.y);
        f[2] = (short)f32_to_bf16_rne(p0.z);
        f[3] = (short)f32_to_bf16_rne(p0.w);
        f[4] = (short)f32_to_bf16_rne(p1.x);
        f[5] = (short)f32_to_bf16_rne(p1.y);
        f[6] = (short)f32_to_bf16_rne(p1.z);
        f[7] = (short)f32_to_bf16_rne(p1.w);
        afr[kk] = f;
    }

    f32x4 acc[8];
    #pragma unroll
    for (int t = 0; t < 8; ++t) acc[t] = (f32x4){0.f, 0.f, 0.f, 0.f};

    #pragma unroll
    for (int kk = 0; kk < 4; ++kk) {
        #pragma unroll
        for (int t = 0; t < 8; ++t) {
            const unsigned short* wp = Wb + (long)(t * 16 + mn) * F + kk * 32 + quad * 8;
            bf16x8 bfr = *(const bf16x8*)wp;
            acc[t] = __builtin_amdgcn_mfma_f32_16x16x32_bf16(afr[kk], bfr, acc[t], 0, 0, 0);
        }
    }

    #pragma unroll
    for (int t = 0; t < 8; ++t) {
        const int col = t * 16 + mn;
        #pragma unroll
        for (int r = 0; r < 4; ++r) {
            const int orow = m0 + quad * 4 + r;
            if (orow < n_rows)
                hp[(long)orow * F + col] = f32_to_bf16_rne(acc[t][r]);
        }
    }
}

// ---------------------------------------------------------------------------
// Kernel A: single-pass per-NODE edge scatter.  pool[d*DCAP + p] = src.
// No LDS, no second pass, no 128-node radix.  Overflow beyond DCAP goes to a
// global spill list (d,s pairs) drained by the gather (cold path, never fires
// for the graded distribution).
// ---------------------------------------------------------------------------
__global__ __launch_bounds__(256) void build_pool_kernel(
        const int* __restrict__ src,
        const int* __restrict__ dst,
        int* __restrict__ cnt,                     // [n_nodes], pre-zeroed
        int* __restrict__ pool,                    // [n_nodes * DCAP]
        int* __restrict__ ovf,                     // [1 + 2*OVFCAP], ovf[0] pre-zeroed
        int n_edges) {
    const int stride = gridDim.x * 256;
    for (int i = blockIdx.x * 256 + threadIdx.x; i < n_edges; i += stride) {
        int d = dst[i], s = src[i];
        int p = atomicAdd(&cnt[d], 1);
        if (p < DCAP) {
            pool[(long)d * DCAP + p] = s;
        } else {                                   // cold correctness path
            int q = atomicAdd(&ovf[0], 1);
            if (q < OVFCAP) { ovf[1 + 2 * q] = d; ovf[2 + 2 * q] = s; }
        }
    }
}

// ---------------------------------------------------------------------------
// Kernel B: per-node gather-aggregate + bias + relu.  One wave owns NPW
// consecutive nodes; edge ids come from the wave-uniform per-node segment
// (scalar loads, SALU address math), each edge is one 256 B row read
// (dword/lane), 8 loads in flight.  Remainder batches are padded with the
// all-zero hp row (index n_nodes) -> no per-edge validity cndmasks anywhere.
// Epilogue writes every out row exactly once (no out memset needed).
// ---------------------------------------------------------------------------
__global__ __launch_bounds__(256) void node_gather_kernel(
        const unsigned short* __restrict__ hp,     // [n_nodes+1][128], row n_nodes = 0
        const int* __restrict__ cnt,
        const int* __restrict__ pool,
        const int* __restrict__ ovf,
        const float* __restrict__ bias,
        float* __restrict__ out,
        int n_nodes) {
    const int lane = threadIdx.x & 63;
    // force wave id into an SGPR so node/segment addressing is compiler-uniform
    const int wv = __builtin_amdgcn_readfirstlane(threadIdx.x >> 6);
    const int n0 = (blockIdx.x * 4 + wv) * NPW;
    const unsigned fofs = lane << 1;               // this lane's 2 feats (ushort units)
    const float2 bv = *(const float2*)(bias + (lane << 1));
    const int novf = ovf[0];

    for (int t = 0; t < NPW; ++t) {
        const int n = n0 + t;
        if (n >= n_nodes) return;
        const int deg = min(cnt[n], DCAP);
        const int* pl = pool + (long)n * DCAP;

        float ax = 0.f, ay = 0.f;
        int i = 0;
        // full batches: no validity checks at all
        for (; i + 8 <= deg; i += 8) {
            unsigned v[8];
            #pragma unroll
            for (int j = 0; j < 8; ++j) {
                int s = pl[i + j];                 // scalar load (uniform addr)
                v[j] = *(const unsigned*)(hp + ((long)s << 7) + fofs);
            }
            #pragma unroll
            for (int j = 0; j < 8; ++j) {
                ax += __uint_as_float(v[j] << 16);
                ay += __uint_as_float(v[j] & 0xffff0000u);
            }
        }
        // remainder: pad to 8 with the zero row (i+j <= 39 < DCAP, always in-bounds)
        if (i < deg) {
            unsigned v[8];
            #pragma unroll
            for (int j = 0; j < 8; ++j) {
                int idx = i + j;
                int sr = pl[idx];                  // speculative, in segment
                int s = (idx < deg) ? sr : n_nodes;
                v[j] = *(const unsigned*)(hp + ((long)s << 7) + fofs);
            }
            #pragma unroll
            for (int j = 0; j < 8; ++j) {
                ax += __uint_as_float(v[j] << 16);
                ay += __uint_as_float(v[j] & 0xffff0000u);
            }
        }
        // drain spill list (uniform branch; novf == 0 in practice)
        if (novf > 0) {
            int ne = min(novf, OVFCAP);
            for (int k = 0; k < ne; ++k) {
                if (ovf[1 + 2 * k] == n) {
                    int s = ovf[2 + 2 * k];
                    unsigned vv = *(const unsigned*)(hp + ((long)s << 7) + fofs);
                    ax += __uint_as_float(vv << 16);
                    ay += __uint_as_float(vv & 0xffff0000u);
                }
            }
        }

        float* o = out + ((long)n << 7) + (lane << 1);
        float rx = fmaxf(ax + bv.x, 0.f);
        float ry = fmaxf(ay + bv.y, 0.f);
        *(float2*)o = make_float2(rx, ry);
    }
}

// ---------------------------------------------------------------------------
// Fallback tier (tiny ws): direct atomic scatter + fp32 GEMM (unchanged).
// ---------------------------------------------------------------------------
__global__ void scatter_add_kernel(const float* __restrict__ h,
                                   const int* __restrict__ src,
                                   const int* __restrict__ dst,
                                   float* __restrict__ agg,
                                   long total) {
    long stride = (long)gridDim.x * blockDim.x;
    for (long i = (long)blockIdx.x * blockDim.x + threadIdx.x; i < total; i += stride) {
        int e    = (int)(i >> 5);
        int lane = (int)(i & 31);
        int s = src[e];
        int d = dst[e];
        float4 v = *(const float4*)(h + (long)s * F + (lane << 2));
        float* o = agg + (long)d * F + (lane << 2);
        unsafeAtomicAdd(o + 0, v.x);
        unsafeAtomicAdd(o + 1, v.y);
        unsafeAtomicAdd(o + 2, v.z);
        unsafeAtomicAdd(o + 3, v.w);
    }
}

__global__ __launch_bounds__(256) void gemm_bias_relu_inplace(
        float* __restrict__ out,
        const float* __restrict__ W,
        const float* __restrict__ bias,
        int n_rows) {
    __shared__ __align__(16) float a_t[KC][BR + 4];
    __shared__ __align__(16) float w_t[KC][F + 4];
    const int tid = threadIdx.x;
    const int tx = tid & 15;
    const int ty = tid >> 4;
    const int row0 = blockIdx.x * BR;
    float acc[4][8];
    #pragma unroll
    for (int i = 0; i < 4; ++i)
        #pragma unroll
        for (int j = 0; j < 8; ++j) acc[i][j] = 0.f;
    for (int kc = 0; kc < F; kc += KC) {
        #pragma unroll
        for (int p = 0; p < 2; ++p) {
            int q = tid + p * 256, r = q >> 3, kq = q & 7;
            int row = row0 + r;
            float4 v = make_float4(0.f, 0.f, 0.f, 0.f);
            if (row < n_rows) v = *(const float4*)(out + (long)row * F + kc + (kq << 2));
            a_t[kq * 4 + 0][r] = v.x; a_t[kq * 4 + 1][r] = v.y;
            a_t[kq * 4 + 2][r] = v.z; a_t[kq * 4 + 3][r] = v.w;
        }
        #pragma unroll
        for (int p = 0; p < 4; ++p) {
            int q = tid + p * 256, j = q >> 3, kq = q & 7;
            float4 v = *(const float4*)(W + (long)j * F + kc + (kq << 2));
            w_t[kq * 4 + 0][j] = v.x; w_t[kq * 4 + 1][j] = v.y;
            w_t[kq * 4 + 2][j] = v.z; w_t[kq * 4 + 3][j] = v.w;
        }
        __syncthreads();
        #pragma unroll
        for (int k = 0; k < KC; ++k) {
            float4 av = *(const float4*)&a_t[k][ty << 2];
            float4 w0 = *(const float4*)&w_t[k][tx << 2];
            float4 w1 = *(const float4*)&w_t[k][64 + (tx << 2)];
            float a4[4] = {av.x, av.y, av.z, av.w};
            float wv[8] = {w0.x, w0.y, w0.z, w0.w, w1.x, w1.y, w1.z, w1.w};
            #pragma unroll
            for (int i = 0; i < 4; ++i)
                #pragma unroll
                for (int j = 0; j < 8; ++j) acc[i][j] += a4[i] * wv[j];
        }
        __syncthreads();
    }
    float4 b0 = *(const float4*)(bias + (tx << 2));
    float4 b1 = *(const float4*)(bias + 64 + (tx << 2));
    #pragma unroll
    for (int i = 0; i < 4; ++i) {
        int row = row0 + (ty << 2) + i;
        if (row < n_rows) {
            float4 r0, r1;
            r0.x = fmaxf(acc[i][0] + b0.x, 0.f); r0.y = fmaxf(acc[i][1] + b0.y, 0.f);
            r0.z = fmaxf(acc[i][2] + b0.z, 0.f); r0.w = fmaxf(acc[i][3] + b0.w, 0.f);
            r1.x = fmaxf(acc[i][4] + b1.x, 0.f); r1.y = fmaxf(acc[i][5] + b1.y, 0.f);
            r1.z = fmaxf(acc[i][6] + b1.z, 0.f); r1.w = fmaxf(acc[i][7] + b1.w, 0.f);
            *(float4*)(out + (long)row * F + (tx << 2)) = r0;
            *(float4*)(out + (long)row * F + 64 + (tx << 2)) = r1;
        }
    }
}

extern "C" void kernel_launch(void* const* d_in, const int* in_sizes, int n_in,
                              void* d_out, int out_size, void* d_ws, size_t ws_size,
                              hipStream_t stream) {
    const float* h   = (const float*)d_in[0];
    const int*   src = (const int*)d_in[1];
    const int*   dst = (const int*)d_in[2];
    const float* W   = (const float*)d_in[3];
    const float* b   = (const float*)d_in[4];
    float* out = (float*)d_out;

    const int n_nodes = in_sizes[0] / F;
    const int n_edges = in_sizes[1];

    // ws layout: cnt | ovf | pool | hp (bf16 h@W^T, +1 zero row) | Wb
    auto al16 = [](size_t x) { return (x + 15) & ~(size_t)15; };
    const size_t off_cnt  = 0;
    const size_t off_ovf  = al16((size_t)n_nodes * 4);
    const size_t off_pool = al16(off_ovf + 4 + (size_t)OVFCAP * 8);
    const size_t off_hp   = al16(off_pool + (size_t)n_nodes * DCAP * 4);
    const size_t off_wb   = al16(off_hp + (size_t)(n_nodes + 1) * F * 2);
    const size_t need     = off_wb + (size_t)F * F * 2;

    if (ws_size >= need && n_nodes > 0) {
        int* cnt  = (int*)((char*)d_ws + off_cnt);
        int* ovf  = (int*)((char*)d_ws + off_ovf);
        int* pool = (int*)((char*)d_ws + off_pool);
        unsigned short* hp = (unsigned short*)((char*)d_ws + off_hp);
        unsigned short* Wb = (unsigned short*)((char*)d_ws + off_wb);

        hipMemsetAsync(cnt, 0, (size_t)n_nodes * 4, stream);
        hipMemsetAsync(ovf, 0, 4, stream);
        hipMemsetAsync(hp + (size_t)n_nodes * F, 0, (size_t)F * 2, stream);  // zero row

        conv_w_kernel<<<(F * F / 4 + 255) / 256, 256, 0, stream>>>(W, Wb, F * F / 4);

        gemm_h_kernel<<<(n_nodes + 63) / 64, 256, 0, stream>>>(h, Wb, hp, n_nodes);

        int bgrid = (n_edges + 255) / 256;
        if (bgrid > 2048) bgrid = 2048;
        if (bgrid < 1) bgrid = 1;
        build_pool_kernel<<<bgrid, 256, 0, stream>>>(src, dst, cnt, pool, ovf, n_edges);

        node_gather_kernel<<<(n_nodes + 4 * NPW - 1) / (4 * NPW), 256, 0, stream>>>(
            hp, cnt, pool, ovf, b, out, n_nodes);
    } else {
        hipMemsetAsync(out, 0, (size_t)out_size * sizeof(float), stream);
        scatter_add_kernel<<<16384, 256, 0, stream>>>(
            h, src, dst, out, (long)n_edges * 32);
        const int gblocks = (n_nodes + BR - 1) / BR;
        gemm_bias_relu_inplace<<<gblocks, 256, 0, stream>>>(out, W, b, n_nodes);
    }
}

// Round 2
// 363.559 us; speedup vs baseline: 1.0004x; 1.0004x over previous
//
#include <hip/hip_runtime.h>

#define F      128       // feature width
#define DCAP   40        // per-node edge capacity (deg ~ Poisson(16); P(deg>40) ~ 1e-24)
#define OVFCAP 32768     // spill-list capacity (cold correctness path, never fires @ graded dist)
#define NPW    16        // nodes per wave in gather
#define EPB    8         // edges per thread in build (batched-MLP atomics)
#define BR     64        // rows per fp32-GEMM block tile (fallback)
#define KC     32        // k-chunk (fallback GEMM)

typedef short bf16x8 __attribute__((ext_vector_type(8)));
typedef float f32x4  __attribute__((ext_vector_type(4)));

__device__ __forceinline__ unsigned short f32_to_bf16_rne(float x) {
    unsigned u = __float_as_uint(x);
    u += 0x7fffu + ((u >> 16) & 1u);
    return (unsigned short)(u >> 16);
}
__device__ __forceinline__ float bf16_to_f32(unsigned short u) {
    return __uint_as_float((unsigned)u << 16);
}

// ---------------------------------------------------------------------------
// Kernel 0: convert W fp32 -> bf16 (64 KB only).
// ---------------------------------------------------------------------------
__global__ __launch_bounds__(256) void conv_w_kernel(
        const float* __restrict__ Wf, unsigned short* __restrict__ Wb, int n4) {
    int i = blockIdx.x * blockDim.x + threadIdx.x;
    if (i < n4) {
        float4 v = *(const float4*)(Wf + 4 * (long)i);
        ushort4 o;
        o.x = f32_to_bf16_rne(v.x);
        o.y = f32_to_bf16_rne(v.y);
        o.z = f32_to_bf16_rne(v.z);
        o.w = f32_to_bf16_rne(v.w);
        *(ushort4*)(Wb + 4 * (long)i) = o;
    }
}

// ---------------------------------------------------------------------------
// Kernel 1: h' = h @ W^T via MFMA bf16 (unchanged).
// Algebraic reorder: segment_sum(h[src]) @ W^T == segment_sum((h@W^T)[src]).
// C layout (measured m89/m91): col=lane&15, row=quad*4+reg.
// ---------------------------------------------------------------------------
__global__ __launch_bounds__(256) void gemm_h_kernel(
        const float* __restrict__ h,
        const unsigned short* __restrict__ Wb,
        unsigned short* __restrict__ hp,          // [n+1][128] bf16 out (row n = zeros)
        int n_rows) {
    const int wave = (blockIdx.x * 256 + threadIdx.x) >> 6;
    const int lane = threadIdx.x & 63;
    const int m0 = wave * 16;
    if (m0 >= n_rows) return;
    const int mn   = lane & 15;
    const int quad = lane >> 4;

    const int rowc = min(m0 + mn, n_rows - 1);
    const float* arow = h + (long)rowc * F + quad * 8;

    bf16x8 afr[4];
    #pragma unroll
    for (int kk = 0; kk < 4; ++kk) {
        float4 p0 = *(const float4*)(arow + kk * 32);
        float4 p1 = *(const float4*)(arow + kk * 32 + 4);
        bf16x8 f;
        f[0] = (short)f32_to_bf16_rne(p0.x);
        f[1] = (short)f32_to_bf16_rne(p0.y);
        f[2] = (short)f32_to_bf16_rne(p0.z);
        f[3] = (short)f32_to_bf16_rne(p0.w);
        f[4] = (short)f32_to_bf16_rne(p1.x);
        f[5] = (short)f32_to_bf16_rne(p1.y);
        f[6] = (short)f32_to_bf16_rne(p1.z);
        f[7] = (short)f32_to_bf16_rne(p1.w);
        afr[kk] = f;
    }

    f32x4 acc[8];
    #pragma unroll
    for (int t = 0; t < 8; ++t) acc[t] = (f32x4){0.f, 0.f, 0.f, 0.f};

    #pragma unroll
    for (int kk = 0; kk < 4; ++kk) {
        #pragma unroll
        for (int t = 0; t < 8; ++t) {
            const unsigned short* wp = Wb + (long)(t * 16 + mn) * F + kk * 32 + quad * 8;
            bf16x8 bfr = *(const bf16x8*)wp;
            acc[t] = __builtin_amdgcn_mfma_f32_16x16x32_bf16(afr[kk], bfr, acc[t], 0, 0, 0);
        }
    }

    #pragma unroll
    for (int t = 0; t < 8; ++t) {
        const int col = t * 16 + mn;
        #pragma unroll
        for (int r = 0; r < 4; ++r) {
            const int orow = m0 + quad * 4 + r;
            if (orow < n_rows)
                hp[(long)orow * F + col] = f32_to_bf16_rne(acc[t][r]);
        }
    }
}

// ---------------------------------------------------------------------------
// Kernel A: single-pass per-node edge scatter, 8 edges per thread.
// All 8 atomicAdd-with-return issued back-to-back (independent -> overlapped
// round-trips), then the 8 scattered stores.  This amortizes the ~800-cycle
// coherence-point latency 8x vs the serial 1-edge/iteration version (146us).
// ---------------------------------------------------------------------------
__global__ __launch_bounds__(256) void build_pool_kernel(
        const int* __restrict__ src,
        const int* __restrict__ dst,
        int* __restrict__ cnt,                     // [n_nodes], pre-zeroed
        int* __restrict__ pool,                    // [n_nodes * DCAP + 64]
        int* __restrict__ ovf,                     // [1 + 2*OVFCAP], ovf[0] pre-zeroed
        int n_edges) {
    const long base = ((long)blockIdx.x * 256 + threadIdx.x) * EPB;
    if (base >= n_edges) return;

    if (base + EPB <= n_edges) {
        int4 d0 = *(const int4*)(dst + base);
        int4 d1 = *(const int4*)(dst + base + 4);
        int4 s0 = *(const int4*)(src + base);
        int4 s1 = *(const int4*)(src + base + 4);
        int d[8] = {d0.x, d0.y, d0.z, d0.w, d1.x, d1.y, d1.z, d1.w};
        int s[8] = {s0.x, s0.y, s0.z, s0.w, s1.x, s1.y, s1.z, s1.w};
        int p[8];
        #pragma unroll
        for (int j = 0; j < 8; ++j) p[j] = atomicAdd(&cnt[d[j]], 1);
        #pragma unroll
        for (int j = 0; j < 8; ++j) {
            if (p[j] < DCAP) {
                pool[(long)d[j] * DCAP + p[j]] = s[j];
            } else {                               // cold correctness path
                int q = atomicAdd(&ovf[0], 1);
                if (q < OVFCAP) { ovf[1 + 2 * q] = d[j]; ovf[2 + 2 * q] = s[j]; }
            }
        }
    } else {                                       // tail (n_edges not /8)
        for (long i = base; i < n_edges; ++i) {
            int d = dst[i], s = src[i];
            int p = atomicAdd(&cnt[d], 1);
            if (p < DCAP) {
                pool[(long)d * DCAP + p] = s;
            } else {
                int q = atomicAdd(&ovf[0], 1);
                if (q < OVFCAP) { ovf[1 + 2 * q] = d; ovf[2 + 2 * q] = s; }
            }
        }
    }
}

// ---------------------------------------------------------------------------
// Kernel B: per-node gather-aggregate + bias + relu.  One wave owns NPW
// consecutive nodes.  Per node: ONE coalesced vector load pulls the whole
// DCAP id segment (lane l holds pl[l]); edge ids are then extracted with
// compile-time-index readlane (SALU, no memory, no lgkm stalls).  All of a
// node's row loads are independent; next node's id vector is prefetched.
// Remainder edges resolve to the all-zero hp row via a scalar cselect -> the
// hot loop is exactly {1 dword load, 2 unpacks, 2 fadds} per edge per lane.
// Epilogue writes each out row exactly once (no out memset needed).
// ---------------------------------------------------------------------------
__global__ __launch_bounds__(256) void node_gather_kernel(
        const unsigned short* __restrict__ hp,     // [n_nodes+1][128], row n_nodes = 0
        const int* __restrict__ cnt,
        const int* __restrict__ pool,              // padded by 64 ints
        const int* __restrict__ ovf,
        const float* __restrict__ bias,
        float* __restrict__ out,
        int n_nodes) {
    const int lane = threadIdx.x & 63;
    const int wv = __builtin_amdgcn_readfirstlane(threadIdx.x >> 6);
    const int n0 = (blockIdx.x * 4 + wv) * NPW;
    if (n0 >= n_nodes) return;
    const float2 bv = *(const float2*)(bias + (lane << 1));
    const int novf = ovf[0];

    // prefetch the 16 degrees for this wave's nodes (lane t holds cnt[n0+t])
    int cidx = n0 + lane;
    if (cidx > n_nodes - 1) cidx = n_nodes - 1;
    const int cval = cnt[cidx];

    // prefetch node 0's id vector
    int myid = pool[(long)n0 * DCAP + lane];

    for (int t = 0; t < NPW; ++t) {
        const int n = n0 + t;
        if (n >= n_nodes) return;
        int deg = __builtin_amdgcn_readlane(cval, t);
        deg = min(deg, DCAP);

        // issue next node's id-vector load early (safe: pool padded by 64)
        int nxt = 0;
        if (t + 1 < NPW) nxt = pool[(long)(n + 1) * DCAP + lane];

        float ax = 0.f, ay = 0.f;
        #pragma unroll
        for (int B = 0; B < (DCAP + 7) / 8; ++B) {
            if (B * 8 >= deg) break;               // uniform branch
            #pragma unroll
            for (int j = 0; j < 8; ++j) {
                const int e = B * 8 + j;           // compile-time lane index
                int sid = __builtin_amdgcn_readlane(myid, e);
                sid = (e < deg) ? sid : n_nodes;   // uniform cselect -> zero row
                unsigned v = *(const unsigned*)(hp + ((long)sid << 7) + (lane << 1));
                ax += __uint_as_float(v << 16);
                ay += __uint_as_float(v & 0xffff0000u);
            }
        }

        // drain spill list (uniform branch; novf == 0 in practice)
        if (novf > 0) {
            int ne = min(novf, OVFCAP);
            for (int k = 0; k < ne; ++k) {
                if (ovf[1 + 2 * k] == n) {
                    int s = ovf[2 + 2 * k];
                    unsigned vv = *(const unsigned*)(hp + ((long)s << 7) + (lane << 1));
                    ax += __uint_as_float(vv << 16);
                    ay += __uint_as_float(vv & 0xffff0000u);
                }
            }
        }

        float* o = out + ((long)n << 7) + (lane << 1);
        float rx = fmaxf(ax + bv.x, 0.f);
        float ry = fmaxf(ay + bv.y, 0.f);
        *(float2*)o = make_float2(rx, ry);

        myid = nxt;
    }
}

// ---------------------------------------------------------------------------
// Fallback tier (tiny ws): direct atomic scatter + fp32 GEMM (unchanged).
// ---------------------------------------------------------------------------
__global__ void scatter_add_kernel(const float* __restrict__ h,
                                   const int* __restrict__ src,
                                   const int* __restrict__ dst,
                                   float* __restrict__ agg,
                                   long total) {
    long stride = (long)gridDim.x * blockDim.x;
    for (long i = (long)blockIdx.x * blockDim.x + threadIdx.x; i < total; i += stride) {
        int e    = (int)(i >> 5);
        int lane = (int)(i & 31);
        int s = src[e];
        int d = dst[e];
        float4 v = *(const float4*)(h + (long)s * F + (lane << 2));
        float* o = agg + (long)d * F + (lane << 2);
        unsafeAtomicAdd(o + 0, v.x);
        unsafeAtomicAdd(o + 1, v.y);
        unsafeAtomicAdd(o + 2, v.z);
        unsafeAtomicAdd(o + 3, v.w);
    }
}

__global__ __launch_bounds__(256) void gemm_bias_relu_inplace(
        float* __restrict__ out,
        const float* __restrict__ W,
        const float* __restrict__ bias,
        int n_rows) {
    __shared__ __align__(16) float a_t[KC][BR + 4];
    __shared__ __align__(16) float w_t[KC][F + 4];
    const int tid = threadIdx.x;
    const int tx = tid & 15;
    const int ty = tid >> 4;
    const int row0 = blockIdx.x * BR;
    float acc[4][8];
    #pragma unroll
    for (int i = 0; i < 4; ++i)
        #pragma unroll
        for (int j = 0; j < 8; ++j) acc[i][j] = 0.f;
    for (int kc = 0; kc < F; kc += KC) {
        #pragma unroll
        for (int p = 0; p < 2; ++p) {
            int q = tid + p * 256, r = q >> 3, kq = q & 7;
            int row = row0 + r;
            float4 v = make_float4(0.f, 0.f, 0.f, 0.f);
            if (row < n_rows) v = *(const float4*)(out + (long)row * F + kc + (kq << 2));
            a_t[kq * 4 + 0][r] = v.x; a_t[kq * 4 + 1][r] = v.y;
            a_t[kq * 4 + 2][r] = v.z; a_t[kq * 4 + 3][r] = v.w;
        }
        #pragma unroll
        for (int p = 0; p < 4; ++p) {
            int q = tid + p * 256, j = q >> 3, kq = q & 7;
            float4 v = *(const float4*)(W + (long)j * F + kc + (kq << 2));
            w_t[kq * 4 + 0][j] = v.x; w_t[kq * 4 + 1][j] = v.y;
            w_t[kq * 4 + 2][j] = v.z; w_t[kq * 4 + 3][j] = v.w;
        }
        __syncthreads();
        #pragma unroll
        for (int k = 0; k < KC; ++k) {
            float4 av = *(const float4*)&a_t[k][ty << 2];
            float4 w0 = *(const float4*)&w_t[k][tx << 2];
            float4 w1 = *(const float4*)&w_t[k][64 + (tx << 2)];
            float a4[4] = {av.x, av.y, av.z, av.w};
            float wv[8] = {w0.x, w0.y, w0.z, w0.w, w1.x, w1.y, w1.z, w1.w};
            #pragma unroll
            for (int i = 0; i < 4; ++i)
                #pragma unroll
                for (int j = 0; j < 8; ++j) acc[i][j] += a4[i] * wv[j];
        }
        __syncthreads();
    }
    float4 b0 = *(const float4*)(bias + (tx << 2));
    float4 b1 = *(const float4*)(bias + 64 + (tx << 2));
    #pragma unroll
    for (int i = 0; i < 4; ++i) {
        int row = row0 + (ty << 2) + i;
        if (row < n_rows) {
            float4 r0, r1;
            r0.x = fmaxf(acc[i][0] + b0.x, 0.f); r0.y = fmaxf(acc[i][1] + b0.y, 0.f);
            r0.z = fmaxf(acc[i][2] + b0.z, 0.f); r0.w = fmaxf(acc[i][3] + b0.w, 0.f);
            r1.x = fmaxf(acc[i][4] + b1.x, 0.f); r1.y = fmaxf(acc[i][5] + b1.y, 0.f);
            r1.z = fmaxf(acc[i][6] + b1.z, 0.f); r1.w = fmaxf(acc[i][7] + b1.w, 0.f);
            *(float4*)(out + (long)row * F + (tx << 2)) = r0;
            *(float4*)(out + (long)row * F + 64 + (tx << 2)) = r1;
        }
    }
}

extern "C" void kernel_launch(void* const* d_in, const int* in_sizes, int n_in,
                              void* d_out, int out_size, void* d_ws, size_t ws_size,
                              hipStream_t stream) {
    const float* h   = (const float*)d_in[0];
    const int*   src = (const int*)d_in[1];
    const int*   dst = (const int*)d_in[2];
    const float* W   = (const float*)d_in[3];
    const float* b   = (const float*)d_in[4];
    float* out = (float*)d_out;

    const int n_nodes = in_sizes[0] / F;
    const int n_edges = in_sizes[1];

    // ws layout: cnt | ovf | pool (+64 pad) | hp (bf16 h@W^T, +1 zero row) | Wb
    auto al16 = [](size_t x) { return (x + 15) & ~(size_t)15; };
    const size_t off_cnt  = 0;
    const size_t off_ovf  = al16((size_t)n_nodes * 4);
    const size_t off_pool = al16(off_ovf + 4 + (size_t)OVFCAP * 8);
    const size_t off_hp   = al16(off_pool + ((size_t)n_nodes * DCAP + 64) * 4);
    const size_t off_wb   = al16(off_hp + (size_t)(n_nodes + 1) * F * 2);
    const size_t need     = off_wb + (size_t)F * F * 2;

    if (ws_size >= need && n_nodes > 0) {
        int* cnt  = (int*)((char*)d_ws + off_cnt);
        int* ovf  = (int*)((char*)d_ws + off_ovf);
        int* pool = (int*)((char*)d_ws + off_pool);
        unsigned short* hp = (unsigned short*)((char*)d_ws + off_hp);
        unsigned short* Wb = (unsigned short*)((char*)d_ws + off_wb);

        hipMemsetAsync(cnt, 0, (size_t)n_nodes * 4, stream);
        hipMemsetAsync(ovf, 0, 4, stream);
        hipMemsetAsync(hp + (size_t)n_nodes * F, 0, (size_t)F * 2, stream);  // zero row

        conv_w_kernel<<<(F * F / 4 + 255) / 256, 256, 0, stream>>>(W, Wb, F * F / 4);

        gemm_h_kernel<<<(n_nodes + 63) / 64, 256, 0, stream>>>(h, Wb, hp, n_nodes);

        int bgrid = (int)((n_edges + (long)EPB * 256 - 1) / ((long)EPB * 256));
        if (bgrid < 1) bgrid = 1;
        build_pool_kernel<<<bgrid, 256, 0, stream>>>(src, dst, cnt, pool, ovf, n_edges);

        node_gather_kernel<<<(n_nodes + 4 * NPW - 1) / (4 * NPW), 256, 0, stream>>>(
            hp, cnt, pool, ovf, b, out, n_nodes);
    } else {
        hipMemsetAsync(out, 0, (size_t)out_size * sizeof(float), stream);
        scatter_add_kernel<<<16384, 256, 0, stream>>>(
            h, src, dst, out, (long)n_edges * 32);
        const int gblocks = (n_nodes + BR - 1) / BR;
        gemm_bias_relu_inplace<<<gblocks, 256, 0, stream>>>(out, W, b, n_nodes);
    }
}